// Round 3
// baseline (35.375 us; speedup 1.0000x reference)
//
#include <hip/hip_runtime.h>

// N=32, C=256, P=256, H=W=7, K=7, PAD=3.
// y[n,p,oh,ow] = Wk[p]*S1[n,oh,ow] + bk[p]*S2[n,oh,ow] + b_adap[p]
//   S1 = channel-summed spatial autocorrelation of x[n] (S1(d)=S1(-d), 25 lags)
//   S2 = clipped-window sums of z, z = channel-sum image of x[n]
// 256 blocks = 8/sample (bid%8==n%8 -> per-sample XCD L2 reuse); each block
// redundantly computes S1/S2 (wall-parallel) and writes a 32-plane y slice.

#define HW 49

__global__ __launch_bounds__(256) void adap_fc_kernel(
    const float* __restrict__ x,   // (32,256,7,7)
    const float* __restrict__ Wk,  // (256,)
    const float* __restrict__ bk,  // (256,)
    const float* __restrict__ ba,  // (256,)
    float* __restrict__ y)         // (32,256,7,7)
{
    const int bid  = blockIdx.x;
    const int n    = bid & 31;
    const int pg   = bid >> 5;
    const int t    = threadIdx.x;
    const int wave = t >> 6;
    const int lane = t & 63;

    __shared__ float lx[256 * HW];   // 50176 B: x[n]
    __shared__ float pw[4][32];      // per-wave reduced S1 (25 used)
    __shared__ float pz[4 * HW];     // per-channel-quarter z partials
    __shared__ float zz[HW];
    __shared__ float s1f[HW];
    __shared__ float s2[HW];
    __shared__ float lwk[32], lbk[32], lba[32];

    // --- stage x[n] (float4, coalesced) ---
    const float4* xn4 = (const float4*)(x + (size_t)n * (256 * HW));
    float4* lx4 = (float4*)lx;
    #pragma unroll
    for (int i = 0; i < 12; ++i) lx4[t + i * 256] = xn4[t + i * 256];
    if (t < 64) lx4[t + 3072] = xn4[t + 3072];
    if (t < 32) { const int p = pg * 32 + t; lwk[t] = Wk[p]; lbk[t] = bk[p]; lba[t] = ba[p]; }
    __syncthreads();

    // --- own channel into registers ---
    float v[HW];
    #pragma unroll
    for (int k = 0; k < HW; ++k) v[k] = lx[t * HW + k];

    // --- 25 canonical autocorr lags (compile-time pruned bounds) ---
    float val[32];
    #pragma unroll
    for (int l = 25; l < 32; ++l) val[l] = 0.f;
    #pragma unroll
    for (int l = 0; l < 25; ++l) {
        const int dh = (l < 4) ? 0 : (l - 4) / 7 + 1;
        const int dw = (l < 4) ? l : (l - 4) % 7 - 3;
        float a = 0.f;
        #pragma unroll
        for (int i = 0; i < 7; ++i) {
            if (i + dh < 0 || i + dh > 6) continue;
            #pragma unroll
            for (int j = 0; j < 7; ++j) {
                if (j + dw < 0 || j + dw > 6) continue;
                a += v[(i + dh) * 7 + (j + dw)] * v[i * 7 + j];
            }
        }
        val[l] = a;
    }

    // --- reduce-scatter across 64 lanes: 32 payload values, 32 shuffles total.
    //     masks 32,16,8,4,2 halve the payload; final mask-1 step finishes.
    //     Result: even lane 2k holds the full cross-lane sum of val[k]. ---
    #pragma unroll
    for (int s = 0; s < 5; ++s) {
        const int m = 32 >> s;   // 32,16,8,4,2
        const int H = 16 >> s;   // 16, 8,4,2,1
        #pragma unroll
        for (int i = 0; i < H; ++i) {
            const float give = (lane & m) ? val[i] : val[H + i];
            const float recv = __shfl_xor(give, m);
            const float keep = (lane & m) ? val[H + i] : val[i];
            val[i] = keep + recv;
        }
    }
    {
        const float give = (lane & 1) ? val[0] : 0.f;
        const float recv = __shfl_xor(give, 1);
        const float keep = (lane & 1) ? 0.f : val[0];
        val[0] = keep + recv;
    }
    if (!(lane & 1) && (lane >> 1) < 25) pw[wave][lane >> 1] = val[0];

    // --- z partials: 196 threads, each sums 64 channels at one position ---
    if (t < 196) {
        const int q = t / 49, pos = t % 49;
        const float* base = lx + (q * 64) * HW + pos;
        float a0 = 0.f, a1 = 0.f, a2 = 0.f, a3 = 0.f;
        #pragma unroll
        for (int i = 0; i < 64; i += 4) {
            a0 += base[(i + 0) * HW];
            a1 += base[(i + 1) * HW];
            a2 += base[(i + 2) * HW];
            a3 += base[(i + 3) * HW];
        }
        pz[t] = (a0 + a1) + (a2 + a3);
    }
    __syncthreads();

    // --- combine: z image; S1 expanded to 49 positions by symmetry ---
    if (t < HW) {
        zz[t] = pz[t] + pz[t + 49] + pz[t + 98] + pz[t + 147];
        int dh = t / 7 - 3, dw = t % 7 - 3;
        if (dh < 0 || (dh == 0 && dw < 0)) { dh = -dh; dw = -dw; }
        const int l = (dh == 0) ? dw : 4 + (dh - 1) * 7 + (dw + 3);
        s1f[t] = pw[0][l] + pw[1][l] + pw[2][l] + pw[3][l];
    }
    __syncthreads();

    // --- S2: clipped-rectangle window sums of zz ---
    if (t < HW) {
        const int doh = t / 7 - 3, dow = t % 7 - 3;
        const int i0 = max(0, doh), i1 = min(6, 6 + doh);
        const int j0 = max(0, dow), j1 = min(6, 6 + dow);
        float s = 0.f;
        for (int i = i0; i <= i1; ++i)
            for (int j = j0; j <= j1; ++j) s += zz[i * 7 + j];
        s2[t] = s;
    }
    __syncthreads();

    // --- epilogue: 32 planes = 392 float4, coalesced ---
    float4* yn4 = (float4*)(y + ((size_t)n * 256 + pg * 32) * HW);
    #pragma unroll
    for (int it = 0; it < 2; ++it) {
        const int i4 = t + it * 256;
        if (i4 < 392) {
            float o[4];
            #pragma unroll
            for (int c = 0; c < 4; ++c) {
                const int idx = i4 * 4 + c;
                const int p = idx / HW, pos = idx - p * HW;
                o[c] = lwk[p] * s1f[pos] + lbk[p] * s2[pos] + lba[p];
            }
            yn4[i4] = make_float4(o[0], o[1], o[2], o[3]);
        }
    }
}

extern "C" void kernel_launch(void* const* d_in, const int* in_sizes, int n_in,
                              void* d_out, int out_size, void* d_ws, size_t ws_size,
                              hipStream_t stream) {
    const float* x  = (const float*)d_in[0];
    const float* Wk = (const float*)d_in[1];
    const float* bk = (const float*)d_in[2];
    const float* ba = (const float*)d_in[3];
    float* y = (float*)d_out;

    adap_fc_kernel<<<256, 256, 0, stream>>>(x, Wk, bk, ba, y);
}

// Round 4
// 12.563 us; speedup vs baseline: 2.8159x; 2.8159x over previous
//
#include <hip/hip_runtime.h>

// N=32, C=256, P=256, H=W=7, K=7, PAD=3.
// y[n,p,oh,ow] = Wk[p]*S1[n,oh,ow] + bk[p]*S2[n,oh,ow] + b_adap[p]
//   S1 = channel-summed spatial autocorrelation of x[n] (S1(d)=S1(-d), 25 lags)
//   S2 = clipped-window sums of z, z = channel-sum image of x[n]
//
// 256 blocks = 8/sample (bid%8==n%8 -> same XCD per sample for L2 reuse of x[n]).
// 1024 threads = 16 waves (4/SIMD) for DS-latency hiding. Thread (c,q):
// channel c = t&255, lag-group q = t>>8 (lags 7/6/6/6). Wave-internal 64-lane
// butterfly per lag (lanes of a wave = 64 consecutive channels).

#define HW 49

__global__ __launch_bounds__(1024, 4) void adap_fc_kernel(
    const float* __restrict__ x,   // (32,256,7,7)
    const float* __restrict__ Wk,  // (256,)
    const float* __restrict__ bk,  // (256,)
    const float* __restrict__ ba,  // (256,)
    float* __restrict__ y)         // (32,256,7,7)
{
    const int bid  = blockIdx.x;
    const int n    = bid & 31;
    const int pg   = bid >> 5;
    const int t    = threadIdx.x;
    const int lane = t & 63;
    const int wg   = (t >> 6) & 3;   // channel-quarter of this wave
    const int q    = t >> 8;         // lag group 0..3

    __shared__ float lx[256 * HW];   // 50176 B: x[n]
    __shared__ float p1[4][25];      // [channel-quarter][lag]
    __shared__ float pz[16][HW];     // z partials
    __shared__ float zz[HW], s1f[HW], s2[HW];
    __shared__ float lwk[32], lbk[32], lba[32];

    // --- stage x[n]: 3136 float4, coalesced across 1024 threads ---
    const float4* xn4 = (const float4*)(x + (size_t)n * (256 * HW));
    float4* lx4 = (float4*)lx;
    #pragma unroll
    for (int i = 0; i < 3; ++i) lx4[t + i * 1024] = xn4[t + i * 1024];
    if (t < 64) lx4[t + 3072] = xn4[t + 3072];
    if (t < 32) { const int p = pg * 32 + t; lwk[t] = Wk[p]; lbk[t] = bk[p]; lba[t] = ba[p]; }
    __syncthreads();

    // --- own channel into registers (compile-time indices) ---
    const int c = t & 255;
    float v[HW];
    #pragma unroll
    for (int k = 0; k < HW; ++k) v[k] = lx[c * HW + k];

    // --- autocorr: each q-group handles its lag subset; wave-uniform guard ---
    #pragma unroll
    for (int l = 0; l < 25; ++l) {
        const int lq = (l < 7) ? 0 : (l < 13) ? 1 : (l < 19) ? 2 : 3;
        if (q == lq) {
            const int dh = (l < 4) ? 0 : (l - 4) / 7 + 1;
            const int dw = (l < 4) ? l : (l - 4) % 7 - 3;
            float a = 0.f;
            #pragma unroll
            for (int i = 0; i < 7; ++i) {
                if (i + dh < 0 || i + dh > 6) continue;      // compile-time pruned
                #pragma unroll
                for (int j = 0; j < 7; ++j) {
                    if (j + dw < 0 || j + dw > 6) continue;  // compile-time pruned
                    a += v[(i + dh) * 7 + (j + dw)] * v[i * 7 + j];
                }
            }
            #pragma unroll
            for (int off = 32; off; off >>= 1) a += __shfl_xor(a, off);
            if (lane == 0) p1[wg][l] = a;   // wave covers channels wg*64..wg*64+63
        }
    }

    // --- z partials: 784 threads, each sums 16 channels at one position ---
    if (t < 784) {
        const int grp = t / 49, pos = t % 49;
        const float* base = lx + (grp * 16) * HW + pos;
        float a0 = 0.f, a1 = 0.f;
        #pragma unroll
        for (int i = 0; i < 16; i += 2) { a0 += base[i * HW]; a1 += base[(i + 1) * HW]; }
        pz[grp][pos] = a0 + a1;
    }
    __syncthreads();

    // --- combine: z image; S1 expanded by symmetry ---
    if (t < HW) {
        float az = 0.f;
        #pragma unroll
        for (int g = 0; g < 16; ++g) az += pz[g][t];
        zz[t] = az;
        int dh = t / 7 - 3, dw = t % 7 - 3;
        if (dh < 0 || (dh == 0 && dw < 0)) { dh = -dh; dw = -dw; }
        const int l = (dh == 0) ? dw : 4 + (dh - 1) * 7 + (dw + 3);
        s1f[t] = p1[0][l] + p1[1][l] + p1[2][l] + p1[3][l];
    }
    __syncthreads();

    // --- S2: clipped-rectangle window sums of zz ---
    if (t < HW) {
        const int doh = t / 7 - 3, dow = t % 7 - 3;
        const int i0 = max(0, doh), i1 = min(6, 6 + doh);
        const int j0 = max(0, dow), j1 = min(6, 6 + dow);
        float s = 0.f;
        for (int i = i0; i <= i1; ++i)
            for (int j = j0; j <= j1; ++j) s += zz[i * 7 + j];
        s2[t] = s;
    }
    __syncthreads();

    // --- epilogue: 32 planes = 392 float4, coalesced ---
    float4* yn4 = (float4*)(y + ((size_t)n * 256 + pg * 32) * HW);
    if (t < 392) {
        float o[4];
        #pragma unroll
        for (int cc = 0; cc < 4; ++cc) {
            const int idx = t * 4 + cc;
            const int p = idx / HW, pos = idx - p * HW;
            o[cc] = lwk[p] * s1f[pos] + lbk[p] * s2[pos] + lba[p];
        }
        yn4[t] = make_float4(o[0], o[1], o[2], o[3]);
    }
}

extern "C" void kernel_launch(void* const* d_in, const int* in_sizes, int n_in,
                              void* d_out, int out_size, void* d_ws, size_t ws_size,
                              hipStream_t stream) {
    const float* x  = (const float*)d_in[0];
    const float* Wk = (const float*)d_in[1];
    const float* bk = (const float*)d_in[2];
    const float* ba = (const float*)d_in[3];
    float* y = (float*)d_out;

    adap_fc_kernel<<<256, 1024, 0, stream>>>(x, Wk, bk, ba, y);
}

// Round 5
// 12.052 us; speedup vs baseline: 2.9351x; 1.0423x over previous
//
#include <hip/hip_runtime.h>

// N=32, C=256, P=256, H=W=7, K=7, PAD=3.
// y[n,p,oh,ow] = Wk[p]*S1[n,oh,ow] + bk[p]*S2[n,oh,ow] + b_adap[p]
//   S1 = channel-summed spatial autocorrelation of x[n] (S1(d)=S1(-d), 25 lags)
//   S2 = clipped-window sums of z, z = channel-sum image of x[n]
//
// Two dispatches:
//  K1: 256 blocks = (n, 32-channel group g). Partial S1(25)+z(49) -> ws[(n*8+g)*80].
//      No redundant compute; each block reads only its contiguous 6.1KB slice.
//  K2: 256 blocks = (n, plane group pg). Combine 8 partials, expand, write y.

#define HW 49

__global__ __launch_bounds__(1024, 4) void k1_partials(
    const float* __restrict__ x,   // (32,256,7,7)
    float* __restrict__ ws)        // (32*8, 80)
{
    const int bid = blockIdx.x;
    const int n = bid & 31, g = bid >> 5;   // bid%8==n%8 -> per-sample XCD locality
    const int t = threadIdx.x;
    const int lane = t & 63;
    const int sub = t >> 6;                 // wave index 0..15 (wave-uniform)

    __shared__ float lx[32 * HW];           // 6272 B: this block's channel slice

    // stage slice: 392 float4, fully coalesced, contiguous
    const float4* xs = (const float4*)(x + ((size_t)n * 256 + g * 32) * HW);
    if (t < 392) ((float4*)lx)[t] = xs[t];
    __syncthreads();

    const int c = lane & 31;                // both 32-lane halves span channels 0..31
    float v[HW];
    #pragma unroll
    for (int k = 0; k < HW; ++k) v[k] = lx[c * HW + k];

    float* wbase = ws + (size_t)(n * 8 + g) * 80;

    // --- S1 lags: owner(l) = l<16 ? l : l-16 (wave-uniform, compile-time bodies) ---
    #pragma unroll
    for (int l = 0; l < 25; ++l) {
        const int own = (l < 16) ? l : (l - 16);
        if (sub == own) {
            const int dh = (l < 4) ? 0 : (l - 4) / 7 + 1;
            const int dw = (l < 4) ? l : (l - 4) % 7 - 3;
            float a = 0.f;
            #pragma unroll
            for (int i = 0; i < 7; ++i) {
                if (i + dh < 0 || i + dh > 6) continue;      // compile-time pruned
                #pragma unroll
                for (int j = 0; j < 7; ++j) {
                    if (j + dw < 0 || j + dw > 6) continue;  // compile-time pruned
                    a += v[(i + dh) * 7 + (j + dw)] * v[i * 7 + j];
                }
            }
            #pragma unroll
            for (int off = 1; off <= 16; off <<= 1) a += __shfl_xor(a, off);
            if (lane == 0) wbase[l] = a;    // sum over channels 0..31 of this slice
        }
    }

    // --- z positions: owner(p) = min(p/3, 15) ---
    #pragma unroll
    for (int p = 0; p < 49; ++p) {
        const int own = (p / 3 > 15) ? 15 : (p / 3);
        if (sub == own) {
            float a = v[p];
            #pragma unroll
            for (int off = 1; off <= 16; off <<= 1) a += __shfl_xor(a, off);
            if (lane == 32) wbase[25 + p] = a;  // lane32 holds identical sum; split stores
        }
    }
}

__global__ __launch_bounds__(512) void k2_epilogue(
    const float* __restrict__ ws,
    const float* __restrict__ Wk,
    const float* __restrict__ bk,
    const float* __restrict__ ba,
    float* __restrict__ y)         // (32,256,7,7)
{
    const int bid = blockIdx.x;
    const int n = bid & 31, pg = bid >> 5;
    const int t = threadIdx.x;

    __shared__ float sm[80];       // [0..24]=S1 lags, [25..73]=z
    __shared__ float rs[HW];       // row-window sums of z
    __shared__ float s1f[HW], s2[HW];
    __shared__ float lwk[32], lbk[32], lba[32];

    if (t < 32) { const int p = pg * 32 + t; lwk[t] = Wk[p]; lbk[t] = bk[p]; lba[t] = ba[p]; }
    if (t < 74) {
        const float* wb = ws + (size_t)n * 8 * 80 + t;
        float a = 0.f;
        #pragma unroll
        for (int g = 0; g < 8; ++g) a += wb[g * 80];
        sm[t] = a;
    }
    __syncthreads();

    if (t < HW) {
        // expand S1 by symmetry
        int dh = t / 7 - 3, dw = t % 7 - 3;
        if (dh < 0 || (dh == 0 && dw < 0)) { dh = -dh; dw = -dw; }
        s1f[t] = sm[(dh == 0) ? dw : 4 + (dh - 1) * 7 + (dw + 3)];
        // separable S2, pass 1: row windows. t = i*7 + ow
        const int i = t / 7, ow = t % 7;
        const int j0 = (ow - 3 < 0) ? 0 : ow - 3, j1 = (ow + 3 > 6) ? 6 : ow + 3;
        float r = 0.f;
        for (int j = j0; j <= j1; ++j) r += sm[25 + i * 7 + j];
        rs[t] = r;
    }
    __syncthreads();

    if (t < HW) {
        // separable S2, pass 2: column windows of rs
        const int oh = t / 7, ow = t % 7;
        const int i0 = (oh - 3 < 0) ? 0 : oh - 3, i1 = (oh + 3 > 6) ? 6 : oh + 3;
        float s = 0.f;
        for (int i = i0; i <= i1; ++i) s += rs[i * 7 + ow];
        s2[t] = s;
    }
    __syncthreads();

    // epilogue: 32 planes = 392 float4, coalesced
    float4* yn4 = (float4*)(y + ((size_t)n * 256 + pg * 32) * HW);
    if (t < 392) {
        float o[4];
        #pragma unroll
        for (int cc = 0; cc < 4; ++cc) {
            const int idx = t * 4 + cc;
            const int p = idx / HW, pos = idx - p * HW;
            o[cc] = lwk[p] * s1f[pos] + lbk[p] * s2[pos] + lba[p];
        }
        yn4[t] = make_float4(o[0], o[1], o[2], o[3]);
    }
}

extern "C" void kernel_launch(void* const* d_in, const int* in_sizes, int n_in,
                              void* d_out, int out_size, void* d_ws, size_t ws_size,
                              hipStream_t stream) {
    const float* x  = (const float*)d_in[0];
    const float* Wk = (const float*)d_in[1];
    const float* bk = (const float*)d_in[2];
    const float* ba = (const float*)d_in[3];
    float* y  = (float*)d_out;
    float* ws = (float*)d_ws;   // 256*80 floats = 80 KB used

    k1_partials<<<256, 1024, 0, stream>>>(x, ws);
    k2_epilogue<<<256, 512, 0, stream>>>(ws, Wk, bk, ba, y);
}